// Round 3
// baseline (325.872 us; speedup 1.0000x reference)
//
#include <hip/hip_runtime.h>
#include <hip/hip_bf16.h>

#define N_NODES 50000
#define N_EDGES 800000
#define DFEAT   128

typedef __attribute__((ext_vector_type(8))) short bf16x8;
typedef __attribute__((ext_vector_type(4))) float f32x4;
typedef unsigned int uint;

// ---------------- CSR build ----------------

__global__ void hist_kernel(const int* __restrict__ dst, int* __restrict__ cnt, int E) {
    int i = blockIdx.x * blockDim.x + threadIdx.x;
    if (i < E) atomicAdd(&cnt[dst[i]], 1);
}

__global__ __launch_bounds__(1024) void chunk_reduce(const int* __restrict__ cnt,
                                                     int* __restrict__ csum, int n) {
    __shared__ int ws[16];
    int tid = threadIdx.x, lane = tid & 63, wid = tid >> 6;
    int i = blockIdx.x * 1024 + tid;
    int v = (i < n) ? cnt[i] : 0;
    #pragma unroll
    for (int m = 1; m < 64; m <<= 1) v += __shfl_xor(v, m, 64);
    if (lane == 0) ws[wid] = v;
    __syncthreads();
    if (tid == 0) {
        int s = 0;
        #pragma unroll
        for (int w = 0; w < 16; ++w) s += ws[w];
        csum[blockIdx.x] = s;
    }
}

__global__ void chunk_scan(const int* __restrict__ csum, int* __restrict__ coff,
                           int* __restrict__ rowptr, int nc, int n) {
    int lane = threadIdx.x;   // 64 threads, nc <= 64
    int v = (lane < nc) ? csum[lane] : 0;
    int s = v;
    #pragma unroll
    for (int off = 1; off < 64; off <<= 1) {
        int t = __shfl_up(s, off, 64);
        if (lane >= off) s += t;
    }
    if (lane < nc) coff[lane] = s - v;     // exclusive chunk offset
    if (lane == 63) rowptr[n] = s;         // grand total
}

__global__ __launch_bounds__(1024) void chunk_prefix(const int* __restrict__ cnt,
                                                     const int* __restrict__ coff,
                                                     int* __restrict__ rowptr,
                                                     int* __restrict__ cursor, int n) {
    __shared__ int wsum[16], woff[16];
    int tid = threadIdx.x, lane = tid & 63, wid = tid >> 6;
    int i = blockIdx.x * 1024 + tid;
    int v = (i < n) ? cnt[i] : 0;
    int s = v;
    #pragma unroll
    for (int off = 1; off < 64; off <<= 1) {
        int t = __shfl_up(s, off, 64);
        if (lane >= off) s += t;
    }
    if (lane == 63) wsum[wid] = s;
    __syncthreads();
    if (tid == 0) {
        int a = 0;
        #pragma unroll
        for (int w = 0; w < 16; ++w) { woff[w] = a; a += wsum[w]; }
    }
    __syncthreads();
    int excl = coff[blockIdx.x] + woff[wid] + (s - v);
    if (i < n) { rowptr[i] = excl; cursor[i] = excl; }
}

__global__ void scatter_kernel(const int* __restrict__ src, const int* __restrict__ dst,
                               const float* __restrict__ ew,
                               int* __restrict__ cursor, int2* __restrict__ edges, int E) {
    int i = blockIdx.x * blockDim.x + threadIdx.x;
    if (i < E) {
        int d = dst[i];
        int pos = atomicAdd(&cursor[d], 1);
        edges[pos] = make_int2(src[i], __float_as_int(ew[i]));
    }
}

// ---------------- f32 -> bf16 conversion ----------------

__device__ __forceinline__ uint pack_bf16x2(float a, float b) {
    __hip_bfloat16 ba = __float2bfloat16(a);
    __hip_bfloat16 bb = __float2bfloat16(b);
    unsigned short ua = *(unsigned short*)&ba;
    unsigned short ub = *(unsigned short*)&bb;
    return (uint)ua | ((uint)ub << 16);
}

__global__ void cvt_kernel(const float* __restrict__ in, uint* __restrict__ out, int n2) {
    int i = blockIdx.x * 256 + threadIdx.x;
    if (i < n2) {
        float2 v = ((const float2*)in)[i];
        out[i] = pack_bf16x2(v.x, v.y);
    }
}

// ------------- weight pack: frag-ordered bf16 for mfma_f32_16x16x32_bf16 -------------
// Bcat[k][n]: k<128 -> wrel[n][k] ; k>=128 -> wroot[n][k-128]
// Bp[((kstep*8 + nfrag)*64 + lane)*8 + j] = Bcat[kstep*32 + (lane>>4)*8 + j][nfrag*16 + (lane&15)]

__global__ void prep_Bpack(const float* __restrict__ wrel, const float* __restrict__ wroot,
                           __hip_bfloat16* __restrict__ Bp) {
    int idx = blockIdx.x * 256 + threadIdx.x;   // 0..32767
    if (idx >= 32768) return;
    int j     = idx & 7;
    int lane  = (idx >> 3) & 63;
    int nfrag = (idx >> 9) & 7;
    int kstep = idx >> 12;
    int k = kstep * 32 + (lane >> 4) * 8 + j;
    int n = nfrag * 16 + (lane & 15);
    float v = (k < 128) ? wrel[n * 128 + k] : wroot[n * 128 + (k - 128)];
    Bp[idx] = __float2bfloat16(v);
}

// ---------------- fused layer: aggregate 64-node tile -> LDS -> MFMA GEMM ----------------
// f: [N][64] uint (bf16x2). Output: relu(([agg|root] @ Bcat) + bias), bf16 or f32.
// Block: 1024 threads (16 waves), tile = 64 nodes. LDS A-tile: [64][68] uints (pad 4).

template<int RELU, int OUTF32>
__global__ __launch_bounds__(1024) void fused_layer(const uint* __restrict__ f,
                                                    const int* __restrict__ rowptr,
                                                    const int2* __restrict__ edges,
                                                    const bf16x8* __restrict__ Bp,
                                                    const float* __restrict__ bias,
                                                    float* __restrict__ outf,
                                                    __hip_bfloat16* __restrict__ outb,
                                                    int N) {
    __shared__ uint As[64][68];
    const int tid  = threadIdx.x;
    const int lane = tid & 63, wid = tid >> 6;   // wid 0..15
    const int tile = blockIdx.x * 64;

    // ---- phase 1: each wave aggregates 4 nodes (all 128 cols, 2 per lane) ----
    #pragma unroll
    for (int q = 0; q < 4; ++q) {
        const int local = wid * 4 + q;
        const int node  = tile + local;
        int beg = 0, end = 0;
        if (node < N) { beg = rowptr[node]; end = rowptr[node + 1]; }
        float ax0 = 0.f, ay0 = 0.f, ax1 = 0.f, ay1 = 0.f;
        float ax2 = 0.f, ay2 = 0.f, ax3 = 0.f, ay3 = 0.f;
        for (int e = beg; e < end; e += 8) {
            int2 ed[8];
            uint v[8];
            float w[8];
            #pragma unroll
            for (int k = 0; k < 8; ++k) {
                int idx = e + k;
                ed[k] = edges[idx < end ? idx : end - 1];
            }
            #pragma unroll
            for (int k = 0; k < 8; ++k) {
                v[k] = f[(size_t)ed[k].x * 64 + lane];
                w[k] = (e + k < end) ? __int_as_float(ed[k].y) : 0.f;
            }
            #pragma unroll
            for (int k = 0; k < 8; ++k) {
                float lo = __uint_as_float(v[k] << 16);
                float hi = __uint_as_float(v[k] & 0xffff0000u);
                if ((k & 3) == 0) { ax0 = fmaf(w[k], lo, ax0); ay0 = fmaf(w[k], hi, ay0); }
                if ((k & 3) == 1) { ax1 = fmaf(w[k], lo, ax1); ay1 = fmaf(w[k], hi, ay1); }
                if ((k & 3) == 2) { ax2 = fmaf(w[k], lo, ax2); ay2 = fmaf(w[k], hi, ay2); }
                if ((k & 3) == 3) { ax3 = fmaf(w[k], lo, ax3); ay3 = fmaf(w[k], hi, ay3); }
            }
        }
        float ax = (ax0 + ax1) + (ax2 + ax3);
        float ay = (ay0 + ay1) + (ay2 + ay3);
        As[local][lane] = pack_bf16x2(ax, ay);
    }
    __syncthreads();

    // ---- phase 2: GEMM  C[64,128] = [Aagg | Aroot][64,256] @ Bcat[256,128] ----
    // 16 waves as 4x4: wr row-group (16 rows), wcol col-group (32 cols = 2 frags)
    const int wr   = wid >> 2;
    const int wcol = wid & 3;
    const int lrow = lane & 15;
    const int lk   = (lane >> 4) * 8;

    int arow_g = tile + wr * 16 + lrow;
    if (arow_g >= N) arow_g = N - 1;
    const short* fb = (const short*)f;
    const short* arow_l = (const short*)&As[wr * 16 + lrow][0];

    f32x4 acc[2];
    acc[0] = (f32x4){0.f, 0.f, 0.f, 0.f};
    acc[1] = (f32x4){0.f, 0.f, 0.f, 0.f};

    #pragma unroll
    for (int ks = 0; ks < 8; ++ks) {
        bf16x8 a;
        if (ks < 4) a = *(const bf16x8*)(arow_l + ks * 32 + lk);
        else        a = *(const bf16x8*)(fb + (size_t)arow_g * 128 + (ks - 4) * 32 + lk);
        #pragma unroll
        for (int ni = 0; ni < 2; ++ni) {
            bf16x8 b = Bp[(ks * 8 + (wcol * 2 + ni)) * 64 + lane];
            acc[ni] = __builtin_amdgcn_mfma_f32_16x16x32_bf16(a, b, acc[ni], 0, 0, 0);
        }
    }

    // ---- epilogue ----
    const int crow = (lane >> 4) * 4;
    const int ccol = lane & 15;
    #pragma unroll
    for (int ni = 0; ni < 2; ++ni) {
        const int col = wcol * 32 + ni * 16 + ccol;
        const float bv = bias[col];
        #pragma unroll
        for (int r = 0; r < 4; ++r) {
            const int row = tile + wr * 16 + crow + r;
            if (row < N) {
                float v = acc[ni][r] + bv;
                if (RELU) v = fmaxf(v, 0.f);
                if (OUTF32) {
                    outf[(size_t)row * 128 + col] = v;
                } else {
                    outb[(size_t)row * 128 + col] = __float2bfloat16(v);
                }
            }
        }
    }
}

// ---------------- launch ----------------

extern "C" void kernel_launch(void* const* d_in, const int* in_sizes, int n_in,
                              void* d_out, int out_size, void* d_ws, size_t ws_size,
                              hipStream_t stream) {
    const float* x   = (const float*)d_in[0];
    const int*  eidx = (const int*)d_in[1];
    const float* ew  = (const float*)d_in[2];
    const float* w1r = (const float*)d_in[3];
    const float* w1t = (const float*)d_in[4];
    const float* b1  = (const float*)d_in[5];
    const float* w2r = (const float*)d_in[6];
    const float* w2t = (const float*)d_in[7];
    const float* b2  = (const float*)d_in[8];
    const float* w3r = (const float*)d_in[9];
    const float* w3t = (const float*)d_in[10];
    const float* b3  = (const float*)d_in[11];
    float* out = (float*)d_out;

    const int N = in_sizes[0] / DFEAT;   // 50000
    const int E = in_sizes[2];           // 800000
    const int NC = (N + 1023) / 1024;    // scan chunks

    char* ws = (char*)d_ws;
    size_t off = 0;
    auto alloc = [&](size_t bytes) -> void* {
        off = (off + 255) & ~(size_t)255;
        void* p = ws + off;
        off += bytes;
        return p;
    };
    int*  cnt    = (int*)alloc((size_t)N * 4);
    int*  rowptr = (int*)alloc((size_t)(N + 1) * 4);
    int*  cursor = (int*)alloc((size_t)N * 4);
    int*  csum   = (int*)alloc(64 * 4);
    int*  coff   = (int*)alloc(64 * 4);
    int2* edges  = (int2*)alloc((size_t)E * 8);
    __hip_bfloat16* Bp1 = (__hip_bfloat16*)alloc(32768 * 2);
    __hip_bfloat16* Bp2 = (__hip_bfloat16*)alloc(32768 * 2);
    __hip_bfloat16* Bp3 = (__hip_bfloat16*)alloc(32768 * 2);
    uint* xb  = (uint*)alloc((size_t)N * 64 * 4);    // bf16 [N][128]
    uint* h1b = (uint*)alloc((size_t)N * 64 * 4);
    uint* h2b = (uint*)alloc((size_t)N * 64 * 4);
    (void)ws_size;

    const int* src = eidx;
    const int* dst = eidx + E;

    // CSR by dst (multi-block scan)
    hipMemsetAsync(cnt, 0, (size_t)N * 4, stream);
    hist_kernel<<<(E + 255) / 256, 256, 0, stream>>>(dst, cnt, E);
    chunk_reduce<<<NC, 1024, 0, stream>>>(cnt, csum, N);
    chunk_scan<<<1, 64, 0, stream>>>(csum, coff, rowptr, NC, N);
    chunk_prefix<<<NC, 1024, 0, stream>>>(cnt, coff, rowptr, cursor, N);
    scatter_kernel<<<(E + 255) / 256, 256, 0, stream>>>(src, dst, ew, cursor, edges, E);

    // feature + weight conversion
    cvt_kernel<<<(N * 64 + 255) / 256, 256, 0, stream>>>(x, xb, N * 64);
    prep_Bpack<<<128, 256, 0, stream>>>(w1r, w1t, Bp1);
    prep_Bpack<<<128, 256, 0, stream>>>(w2r, w2t, Bp2);
    prep_Bpack<<<128, 256, 0, stream>>>(w3r, w3t, Bp3);

    const int fusedGrid = (N + 63) / 64;   // 782

    fused_layer<1, 0><<<fusedGrid, 1024, 0, stream>>>(xb, rowptr, edges, (const bf16x8*)Bp1,
                                                      b1, nullptr, (__hip_bfloat16*)h1b, N);
    fused_layer<1, 0><<<fusedGrid, 1024, 0, stream>>>(h1b, rowptr, edges, (const bf16x8*)Bp2,
                                                      b2, nullptr, (__hip_bfloat16*)h2b, N);
    fused_layer<0, 1><<<fusedGrid, 1024, 0, stream>>>(h2b, rowptr, edges, (const bf16x8*)Bp3,
                                                      b3, out, nullptr, N);
}